// Round 15
// baseline (1496.943 us; speedup 1.0000x reference)
//
#include <hip/hip_runtime.h>
#include <hip/hip_bf16.h>

#define NN 512      // nodes per graph
#define NE 8192     // edges per graph
#define NG 128      // graphs (B*G)
#define FH 128      // feature/hidden dim
#define BN_EPS 1e-5f

typedef __attribute__((ext_vector_type(8))) short s8v;            // 8 bf16 = 4 VGPRs
typedef __attribute__((ext_vector_type(4))) float f4v;            // MFMA C/D
typedef __attribute__((ext_vector_type(4))) unsigned short us4v;  // native ushort4

__device__ inline unsigned short f2bf(float x) {   // RNE fp32 -> bf16 bits
    unsigned u = __float_as_uint(x);
    unsigned r = (u + 0x7fffu + ((u >> 16) & 1u)) >> 16;
    return (unsigned short)r;
}
__device__ inline float bf2f(unsigned short h) { return __uint_as_float(((unsigned)h) << 16); }
__device__ inline float4 bf4_to_f4(const ushort4& v) {
    return make_float4(bf2f(v.x), bf2f(v.y), bf2f(v.z), bf2f(v.w));
}

// ---------------- K1: degrees + norms + CSR (src+dst); blocks >= NG pack W ----------------
__global__ __launch_bounds__(1024) void k_build(const int* __restrict__ edges,
                                                float* __restrict__ rs_out,
                                                float* __restrict__ rs_in,
                                                int* __restrict__ row_ofs,
                                                int* __restrict__ csr_src,
                                                int* __restrict__ csr_dst,
                                                const float* __restrict__ W0,
                                                const float* __restrict__ W1,
                                                unsigned short* __restrict__ WP) {
    int g = blockIdx.x;
    int tid = threadIdx.x;

    if (g >= NG) {
        int which = g - NG;
        const float* W = which ? W1 : W0;
        for (int task = tid; task < 2048; task += 1024) {
            int t = task >> 6;            // 0..31  (nt*4+kk)
            int lane = task & 63;
            int nt = t >> 2, kk = t & 3;
            int n = nt * 16 + (lane & 15);
            int k0 = kk * 32 + (lane >> 4) * 8;
            unsigned short* dh = WP + ((size_t)which * 2 + 0) * 16384 + ((size_t)t * 64 + lane) * 8;
            unsigned short* dl = WP + ((size_t)which * 2 + 1) * 16384 + ((size_t)t * 64 + lane) * 8;
#pragma unroll
            for (int j = 0; j < 8; j++) {
                float v = W[(size_t)(k0 + j) * FH + n];
                unsigned short h = f2bf(v);
                dh[j] = h;
                dl[j] = f2bf(v - bf2f(h));
            }
        }
        return;
    }

    const int* src = edges + (size_t)g * 2 * NE;
    const int* dst = src + NE;

    __shared__ int degO[NN], degI[NN];
    __shared__ int scanA[NN], scanB[NN];
    __shared__ int fill[NN];
    __shared__ int csr_lds[NE];          // 32 KB
    __shared__ int dst_lds[NE];          // 32 KB

    for (int i = tid; i < NN; i += 1024) { degO[i] = 0; degI[i] = 0; }
    __syncthreads();
    for (int u = tid; u < NE / 4; u += 1024) {
        int4 s = ((const int4*)src)[u];
        int4 d = ((const int4*)dst)[u];
        atomicAdd(&degO[s.x], 1); atomicAdd(&degO[s.y], 1);
        atomicAdd(&degO[s.z], 1); atomicAdd(&degO[s.w], 1);
        atomicAdd(&degI[d.x], 1); atomicAdd(&degI[d.y], 1);
        atomicAdd(&degI[d.z], 1); atomicAdd(&degI[d.w], 1);
    }
    __syncthreads();
    for (int i = tid; i < NN; i += 1024) {
        int dO = degO[i], dI = degI[i];
        rs_out[g * NN + i] = rsqrtf((float)max(dO, 1));
        rs_in [g * NN + i] = rsqrtf((float)max(dI, 1));
        scanA[i] = dI;
    }
    __syncthreads();
    int* sA = scanA; int* sB = scanB;
    for (int off = 1; off < NN; off <<= 1) {
        for (int i = tid; i < NN; i += 1024) {
            int v = sA[i];
            if (i >= off) v += sA[i - off];
            sB[i] = v;
        }
        __syncthreads();
        int* t = sA; sA = sB; sB = t;
    }
    for (int i = tid; i < NN; i += 1024) {
        int excl = (i == 0) ? 0 : sA[i - 1];
        fill[i] = excl;
        row_ofs[g * 513 + i] = excl;
    }
    if (tid == 0) row_ofs[g * 513 + NN] = sA[NN - 1];
    __syncthreads();
    for (int u = tid; u < NE / 4; u += 1024) {
        int4 s = ((const int4*)src)[u];
        int4 d = ((const int4*)dst)[u];
        int p0 = atomicAdd(&fill[d.x], 1); csr_lds[p0] = s.x; dst_lds[p0] = d.x;
        int p1 = atomicAdd(&fill[d.y], 1); csr_lds[p1] = s.y; dst_lds[p1] = d.y;
        int p2 = atomicAdd(&fill[d.z], 1); csr_lds[p2] = s.z; dst_lds[p2] = d.z;
        int p3 = atomicAdd(&fill[d.w], 1); csr_lds[p3] = s.w; dst_lds[p3] = d.w;
    }
    __syncthreads();
    for (int u = tid; u < NE / 4; u += 1024) {
        ((int4*)(csr_src + (size_t)g * NE))[u] = ((const int4*)csr_lds)[u];
        ((int4*)(csr_dst + (size_t)g * NE))[u] = ((const int4*)dst_lds)[u];
    }
    if (g == NG - 1 && tid < 16) {
        csr_src[(size_t)NG * NE + tid] = 0;
        csr_dst[(size_t)NG * NE + tid] = 0;
    }
}

// ---------------- K2: Yb(bf16) = (feats(fp32) @ W0) * rs  (hi/lo split, 3 MFMA) ----------------
#define XPITCH 136
__global__ __launch_bounds__(256) void k_gemm_f32(const float* __restrict__ X,
                                                  const unsigned short* __restrict__ WPh,
                                                  const unsigned short* __restrict__ WPl,
                                                  const float* __restrict__ rs,
                                                  unsigned short* __restrict__ Yb) {
    __shared__ unsigned short xh[64 * XPITCH];   // 17 KB
    __shared__ unsigned short xl[64 * XPITCH];   // 17 KB
    int tid = threadIdx.x;
    size_t r0 = (size_t)blockIdx.x * NN + (size_t)blockIdx.y * 64;

    const float4* Xv = (const float4*)(X + r0 * FH);
#pragma unroll
    for (int i = 0; i < 8; i++) {
        int u = tid + i * 256;                 // 2048 float4 = 64x128
        int row = u >> 5, c4 = (u & 31) * 4;
        float4 v = Xv[u];
        int off = row * XPITCH + c4;
        unsigned short h0 = f2bf(v.x), h1 = f2bf(v.y), h2 = f2bf(v.z), h3 = f2bf(v.w);
        xh[off + 0] = h0; xh[off + 1] = h1; xh[off + 2] = h2; xh[off + 3] = h3;
        xl[off + 0] = f2bf(v.x - bf2f(h0));
        xl[off + 1] = f2bf(v.y - bf2f(h1));
        xl[off + 2] = f2bf(v.z - bf2f(h2));
        xl[off + 3] = f2bf(v.w - bf2f(h3));
    }
    __syncthreads();

    int lane = tid & 63, w = tid >> 6;
    int quad = lane >> 4, m = lane & 15;
    int arow = w * 16 + m;

    f4v acc[8];
#pragma unroll
    for (int nt = 0; nt < 8; nt++) acc[nt] = (f4v){0.f, 0.f, 0.f, 0.f};

#pragma unroll
    for (int kk = 0; kk < 4; kk++) {
        s8v ah = *(const s8v*)&xh[arow * XPITCH + kk * 32 + quad * 8];
        s8v al = *(const s8v*)&xl[arow * XPITCH + kk * 32 + quad * 8];
#pragma unroll
        for (int nt = 0; nt < 8; nt++) {
            s8v bh = *(const s8v*)(WPh + ((size_t)(nt * 4 + kk) * 64 + lane) * 8);
            s8v bl = *(const s8v*)(WPl + ((size_t)(nt * 4 + kk) * 64 + lane) * 8);
            acc[nt] = __builtin_amdgcn_mfma_f32_16x16x32_bf16(ah, bh, acc[nt], 0, 0, 0);
            acc[nt] = __builtin_amdgcn_mfma_f32_16x16x32_bf16(al, bh, acc[nt], 0, 0, 0);
            acc[nt] = __builtin_amdgcn_mfma_f32_16x16x32_bf16(ah, bl, acc[nt], 0, 0, 0);
        }
    }

    int orow = w * 16 + quad * 4;
    float4 rsv = *(const float4*)(rs + r0 + orow);
#pragma unroll
    for (int nt = 0; nt < 8; nt++) {
        Yb[(r0 + orow + 0) * FH + nt * 16 + m] = f2bf(acc[nt][0] * rsv.x);
        Yb[(r0 + orow + 1) * FH + nt * 16 + m] = f2bf(acc[nt][1] * rsv.y);
        Yb[(r0 + orow + 2) * FH + nt * 16 + m] = f2bf(acc[nt][2] * rsv.z);
        Yb[(r0 + orow + 3) * FH + nt * 16 + m] = f2bf(acc[nt][3] * rsv.w);
    }
}

// ---------------- K3: FUSED LDS-atomic aggregate (native ds_add_f32) + bf16 MFMA gemm2 ----------------
// Block (g, sb) owns slab rows [64sb, 64sb+64). accI bank-interleaved:
// feature f of row d lives at accI[d*128 + (f%4)*32 + f/4] -> ds_add bank = lane, conflict-free.
// unsafeAtomicAdd emits native ds_add_f32 (plain atomicAdd CAS-loops -> R14's 694 us disaster).
__global__ __launch_bounds__(512) void k_fused(const unsigned short* __restrict__ Y1,
                                               const int* __restrict__ row_ofs,
                                               const int* __restrict__ csr_src,
                                               const int* __restrict__ csr_dst,
                                               const float* __restrict__ rs_in,
                                               const float* __restrict__ rs_out,
                                               const float* __restrict__ bias,
                                               const unsigned short* __restrict__ WPh,
                                               const unsigned short* __restrict__ WPl,
                                               unsigned short* __restrict__ Y2) {
    int g  = blockIdx.x;
    int sb = blockIdx.y;   // 0..7
    int tid = threadIdx.x;
    int lane = tid & 31;
    int grp  = tid >> 5;   // 0..15
    int base = sb * 64;

    __shared__ float accI[64 * FH];              // 32 KB interleaved fp32 accumulator
    __shared__ unsigned short hs[64 * XPITCH];   // 17 KB bf16 h-tile (natural layout)
    __shared__ float rsin_s[64];

    for (int i = tid; i < 64 * FH; i += 512) accI[i] = 0.f;
    if (tid < 64) rsin_s[tid] = rs_in[g * NN + base + tid];
    __syncthreads();

    {   // ---- scatter phase: group walks a contiguous chunk of the slab's edges ----
        int eS = row_ofs[g * 513 + base];
        int eE = row_ofs[g * 513 + base + 64];
        int Es = eE - eS;
        int myS = eS + (Es * grp) / 16;
        int myE = eS + (Es * (grp + 1)) / 16;
        const ushort4* Yv = (const ushort4*)(Y1 + (size_t)g * NN * FH);
        const int* cs = csr_src + (size_t)g * NE;
        const int* cd = csr_dst + (size_t)g * NE;

        int e = myS;
        for (; e + 4 <= myE; e += 4) {
            int s0 = cs[e], s1 = cs[e+1], s2 = cs[e+2], s3 = cs[e+3];
            int d0 = cd[e] - base, d1 = cd[e+1] - base, d2 = cd[e+2] - base, d3 = cd[e+3] - base;
            ushort4 y0 = Yv[s0 * 32 + lane];
            ushort4 y1 = Yv[s1 * 32 + lane];
            ushort4 y2 = Yv[s2 * 32 + lane];
            ushort4 y3 = Yv[s3 * 32 + lane];
            float4 v0 = bf4_to_f4(y0), v1 = bf4_to_f4(y1), v2 = bf4_to_f4(y2), v3 = bf4_to_f4(y3);
            unsafeAtomicAdd(&accI[d0 * FH +       lane], v0.x);
            unsafeAtomicAdd(&accI[d0 * FH +  32 + lane], v0.y);
            unsafeAtomicAdd(&accI[d0 * FH +  64 + lane], v0.z);
            unsafeAtomicAdd(&accI[d0 * FH +  96 + lane], v0.w);
            unsafeAtomicAdd(&accI[d1 * FH +       lane], v1.x);
            unsafeAtomicAdd(&accI[d1 * FH +  32 + lane], v1.y);
            unsafeAtomicAdd(&accI[d1 * FH +  64 + lane], v1.z);
            unsafeAtomicAdd(&accI[d1 * FH +  96 + lane], v1.w);
            unsafeAtomicAdd(&accI[d2 * FH +       lane], v2.x);
            unsafeAtomicAdd(&accI[d2 * FH +  32 + lane], v2.y);
            unsafeAtomicAdd(&accI[d2 * FH +  64 + lane], v2.z);
            unsafeAtomicAdd(&accI[d2 * FH +  96 + lane], v2.w);
            unsafeAtomicAdd(&accI[d3 * FH +       lane], v3.x);
            unsafeAtomicAdd(&accI[d3 * FH +  32 + lane], v3.y);
            unsafeAtomicAdd(&accI[d3 * FH +  64 + lane], v3.z);
            unsafeAtomicAdd(&accI[d3 * FH +  96 + lane], v3.w);
        }
        for (; e < myE; e++) {
            int s = cs[e], d = cd[e] - base;
            float4 v = bf4_to_f4(Yv[s * 32 + lane]);
            unsafeAtomicAdd(&accI[d * FH +       lane], v.x);
            unsafeAtomicAdd(&accI[d * FH +  32 + lane], v.y);
            unsafeAtomicAdd(&accI[d * FH +  64 + lane], v.z);
            unsafeAtomicAdd(&accI[d * FH +  96 + lane], v.w);
        }
    }
    __syncthreads();

    // ---- epilogue A: accI -> hs bf16 (relu(rs*acc + b)), conflict-free reads ----
    {
        float4 bv = ((const float4*)bias)[lane];
        for (int r = grp; r < 64; r += 16) {
            float rr = rsin_s[r];
            us4v h;
            h.x = f2bf(fmaxf(fmaf(rr, accI[r * FH +       lane], bv.x), 0.f));
            h.y = f2bf(fmaxf(fmaf(rr, accI[r * FH +  32 + lane], bv.y), 0.f));
            h.z = f2bf(fmaxf(fmaf(rr, accI[r * FH +  64 + lane], bv.z), 0.f));
            h.w = f2bf(fmaxf(fmaf(rr, accI[r * FH +  96 + lane], bv.w), 0.f));
            *(us4v*)&hs[r * XPITCH + lane * 4] = h;
        }
    }
    __syncthreads();

    // ---- gemm phase: 8 waves; wave = (m-tile = w&3, n-half = w>>2) ----
    int lane64 = tid & 63, w = tid >> 6;   // w: 0..7
    int quad = lane64 >> 4, m = lane64 & 15;
    int mt = w & 3, nh = w >> 2;
    int arow = mt * 16 + m;
    size_t r0 = (size_t)g * NN + base;

    f4v acc[4];
#pragma unroll
    for (int j = 0; j < 4; j++) acc[j] = (f4v){0.f, 0.f, 0.f, 0.f};

#pragma unroll
    for (int kk = 0; kk < 4; kk++) {
        s8v ah = *(const s8v*)&hs[arow * XPITCH + kk * 32 + quad * 8];
#pragma unroll
        for (int j = 0; j < 4; j++) {
            int nt = nh * 4 + j;
            s8v bh = *(const s8v*)(WPh + ((size_t)(nt * 4 + kk) * 64 + lane64) * 8);
            s8v bl = *(const s8v*)(WPl + ((size_t)(nt * 4 + kk) * 64 + lane64) * 8);
            acc[j] = __builtin_amdgcn_mfma_f32_16x16x32_bf16(ah, bh, acc[j], 0, 0, 0);
            acc[j] = __builtin_amdgcn_mfma_f32_16x16x32_bf16(ah, bl, acc[j], 0, 0, 0);
        }
    }

    int orow = mt * 16 + quad * 4;
    float4 rsv = *(const float4*)(rs_out + r0 + orow);
#pragma unroll
    for (int j = 0; j < 4; j++) {
        int nt = nh * 4 + j;
        Y2[(r0 + orow + 0) * FH + nt * 16 + m] = f2bf(acc[j][0] * rsv.x);
        Y2[(r0 + orow + 1) * FH + nt * 16 + m] = f2bf(acc[j][1] * rsv.y);
        Y2[(r0 + orow + 2) * FH + nt * 16 + m] = f2bf(acc[j][2] * rsv.z);
        Y2[(r0 + orow + 3) * FH + nt * 16 + m] = f2bf(acc[j][3] * rsv.w);
    }
}

// ---------------- K4: LDS-atomic aggregate (conv2 epilogue) + node-sum -> partial[g][sb] ----------------
__global__ __launch_bounds__(512) void k_gather_mean(const unsigned short* __restrict__ Yb,
                                                     const int* __restrict__ row_ofs,
                                                     const int* __restrict__ csr_src,
                                                     const int* __restrict__ csr_dst,
                                                     const float* __restrict__ rs_in,
                                                     const float* __restrict__ bias,
                                                     float* __restrict__ partial) {
    int g  = blockIdx.x;
    int sb = blockIdx.y;
    int tid = threadIdx.x;
    int lane = tid & 31;
    int grp  = tid >> 5;   // 0..15
    int base = sb * 64;

    __shared__ float accI[64 * FH];    // 32 KB
    __shared__ float4 red[16][32];     // 8 KB
    __shared__ float rsin_s[64];

    for (int i = tid; i < 64 * FH; i += 512) accI[i] = 0.f;
    if (tid < 64) rsin_s[tid] = rs_in[g * NN + base + tid];
    __syncthreads();

    {   // ---- scatter phase ----
        int eS = row_ofs[g * 513 + base];
        int eE = row_ofs[g * 513 + base + 64];
        int Es = eE - eS;
        int myS = eS + (Es * grp) / 16;
        int myE = eS + (Es * (grp + 1)) / 16;
        const ushort4* Yv = (const ushort4*)(Yb + (size_t)g * NN * FH);
        const int* cs = csr_src + (size_t)g * NE;
        const int* cd = csr_dst + (size_t)g * NE;

        int e = myS;
        for (; e + 4 <= myE; e += 4) {
            int s0 = cs[e], s1 = cs[e+1], s2 = cs[e+2], s3 = cs[e+3];
            int d0 = cd[e] - base, d1 = cd[e+1] - base, d2 = cd[e+2] - base, d3 = cd[e+3] - base;
            ushort4 y0 = Yv[s0 * 32 + lane];
            ushort4 y1 = Yv[s1 * 32 + lane];
            ushort4 y2 = Yv[s2 * 32 + lane];
            ushort4 y3 = Yv[s3 * 32 + lane];
            float4 v0 = bf4_to_f4(y0), v1 = bf4_to_f4(y1), v2 = bf4_to_f4(y2), v3 = bf4_to_f4(y3);
            unsafeAtomicAdd(&accI[d0 * FH +       lane], v0.x);
            unsafeAtomicAdd(&accI[d0 * FH +  32 + lane], v0.y);
            unsafeAtomicAdd(&accI[d0 * FH +  64 + lane], v0.z);
            unsafeAtomicAdd(&accI[d0 * FH +  96 + lane], v0.w);
            unsafeAtomicAdd(&accI[d1 * FH +       lane], v1.x);
            unsafeAtomicAdd(&accI[d1 * FH +  32 + lane], v1.y);
            unsafeAtomicAdd(&accI[d1 * FH +  64 + lane], v1.z);
            unsafeAtomicAdd(&accI[d1 * FH +  96 + lane], v1.w);
            unsafeAtomicAdd(&accI[d2 * FH +       lane], v2.x);
            unsafeAtomicAdd(&accI[d2 * FH +  32 + lane], v2.y);
            unsafeAtomicAdd(&accI[d2 * FH +  64 + lane], v2.z);
            unsafeAtomicAdd(&accI[d2 * FH +  96 + lane], v2.w);
            unsafeAtomicAdd(&accI[d3 * FH +       lane], v3.x);
            unsafeAtomicAdd(&accI[d3 * FH +  32 + lane], v3.y);
            unsafeAtomicAdd(&accI[d3 * FH +  64 + lane], v3.z);
            unsafeAtomicAdd(&accI[d3 * FH +  96 + lane], v3.w);
        }
        for (; e < myE; e++) {
            int s = cs[e], d = cd[e] - base;
            float4 v = bf4_to_f4(Yv[s * 32 + lane]);
            unsafeAtomicAdd(&accI[d * FH +       lane], v.x);
            unsafeAtomicAdd(&accI[d * FH +  32 + lane], v.y);
            unsafeAtomicAdd(&accI[d * FH +  64 + lane], v.z);
            unsafeAtomicAdd(&accI[d * FH +  96 + lane], v.w);
        }
    }
    __syncthreads();

    // ---- epilogue: relu(rs*acc + b), sum over the slab's 64 rows ----
    float4 bv = ((const float4*)bias)[lane];
    float4 s = make_float4(0.f, 0.f, 0.f, 0.f);
#pragma unroll
    for (int i = 0; i < 4; i++) {
        int r = grp * 4 + i;
        float rr = rsin_s[r];
        s.x += fmaxf(fmaf(rr, accI[r * FH +       lane], bv.x), 0.f);
        s.y += fmaxf(fmaf(rr, accI[r * FH +  32 + lane], bv.y), 0.f);
        s.z += fmaxf(fmaf(rr, accI[r * FH +  64 + lane], bv.z), 0.f);
        s.w += fmaxf(fmaf(rr, accI[r * FH +  96 + lane], bv.w), 0.f);
    }
    red[grp][lane] = s;
    __syncthreads();
    if (tid < 32) {
        float4 t = red[0][tid];
#pragma unroll
        for (int j = 1; j < 16; j++) {
            float4 u = red[j][tid];
            t.x += u.x; t.y += u.y; t.z += u.z; t.w += u.w;
        }
        *(float4*)(partial + (((size_t)g * 8 + sb) * FH) + tid * 4) = t;
    }
}

// ---------------- K5: z = (sum partials)/512 @ Wt + bt; BN eval; relu ----------------
__global__ __launch_bounds__(128) void k_head(const float* __restrict__ partial,
                                              const float* __restrict__ Wt,
                                              const float* __restrict__ bt,
                                              const float* __restrict__ gamma,
                                              const float* __restrict__ beta,
                                              const float* __restrict__ rmean,
                                              const float* __restrict__ rvar,
                                              float* __restrict__ out) {
    int g = blockIdx.x;
    int j = threadIdx.x;
    __shared__ float e[FH];
    float acc8 = 0.f;
#pragma unroll
    for (int q = 0; q < 8; q++) acc8 += partial[((size_t)g * 8 + q) * FH + j];
    e[j] = acc8 * (1.0f / (float)NN);
    __syncthreads();
    float acc = bt[j];
#pragma unroll 8
    for (int k = 0; k < FH; k++) acc += e[k] * Wt[(size_t)k * FH + j];
    float z = gamma[j] * (acc - rmean[j]) * rsqrtf(rvar[j] + BN_EPS) + beta[j];
    out[g * FH + j] = fmaxf(z, 0.f);
}

extern "C" void kernel_launch(void* const* d_in, const int* in_sizes, int n_in,
                              void* d_out, int out_size, void* d_ws, size_t ws_size,
                              hipStream_t stream) {
    const float* feats = (const float*)d_in[0];
    const int*   edges = (const int*)d_in[1];
    const float* W0    = (const float*)d_in[2];
    const float* b0    = (const float*)d_in[3];
    const float* W1    = (const float*)d_in[4];
    const float* b1    = (const float*)d_in[5];
    const float* Wt    = (const float*)d_in[6];
    const float* bt    = (const float*)d_in[7];
    const float* gamma = (const float*)d_in[8];
    const float* beta  = (const float*)d_in[9];
    const float* rmean = (const float*)d_in[10];
    const float* rvar  = (const float*)d_in[11];
    float* out = (float*)d_out;

    // workspace layout
    char* w = (char*)d_ws;
    float* rs_out  = (float*)w;   w += sizeof(float) * NG * NN;
    float* rs_in   = (float*)w;   w += sizeof(float) * NG * NN;
    int*   row_ofs = (int*)w;     w += sizeof(int) * NG * 520;
    int*   csr_src = (int*)w;     w += sizeof(int) * ((size_t)NG * NE + 16);
    int*   csr_dst = (int*)w;     w += sizeof(int) * ((size_t)NG * NE + 16);
    unsigned short* WP = (unsigned short*)w;  w += sizeof(unsigned short) * 4 * 16384; // 128 KB
    unsigned short* Y1 = (unsigned short*)w;  w += sizeof(unsigned short) * (size_t)NG * NN * FH; // 16 MB
    unsigned short* Y2 = (unsigned short*)w;  w += sizeof(unsigned short) * (size_t)NG * NN * FH; // 16 MB
    float* partial = (float*)w;   w += sizeof(float) * NG * 8 * FH;

    unsigned short* WPh0 = WP;
    unsigned short* WPl0 = WP + 16384;
    unsigned short* WPh1 = WP + 32768;
    unsigned short* WPl1 = WP + 49152;

    // K1: build norms + CSR; 2 extra blocks pack W0/W1
    k_build<<<NG + 2, 1024, 0, stream>>>(edges, rs_out, rs_in, row_ofs, csr_src, csr_dst,
                                         W0, W1, WP);

    // K2: conv1 gemm (feats -> Y1), XCD = g%8
    k_gemm_f32<<<dim3(NG, 8), 256, 0, stream>>>(feats, WPh0, WPl0, rs_out, Y1);

    // K3: fused conv1-aggregate (native LDS fp atomics) + conv2-gemm (Y1 -> Y2)
    k_fused<<<dim3(NG, 8), 512, 0, stream>>>(Y1, row_ofs, csr_src, csr_dst,
                                             rs_in, rs_out, b0, WPh1, WPl1, Y2);

    // K4: conv2 aggregate (native LDS fp atomics) + node-mean partials
    k_gather_mean<<<dim3(NG, 8), 512, 0, stream>>>(Y2, row_ofs, csr_src, csr_dst, rs_in, b1, partial);

    // K5: head
    k_head<<<NG, 128, 0, stream>>>(partial, Wt, bt, gamma, beta, rmean, rvar, out);

    (void)in_sizes; (void)n_in; (void)out_size; (void)ws_size;
}

// Round 16
// 191.094 us; speedup vs baseline: 7.8335x; 7.8335x over previous
//
#include <hip/hip_runtime.h>
#include <hip/hip_bf16.h>

#define NN 512      // nodes per graph
#define NE 8192     // edges per graph
#define NG 128      // graphs (B*G)
#define FH 128      // feature/hidden dim
#define APITCH 132  // A-chunk int pitch (2-way bank alias = free)
#define XPITCH 136
#define BN_EPS 1e-5f

typedef __attribute__((ext_vector_type(8))) short s8v;            // 8 bf16 = 4 VGPRs
typedef __attribute__((ext_vector_type(4))) float f4v;            // MFMA C/D
typedef __attribute__((ext_vector_type(4))) unsigned short us4v;  // native ushort4

__device__ inline unsigned short f2bf(float x) {   // RNE fp32 -> bf16 bits
    unsigned u = __float_as_uint(x);
    unsigned r = (u + 0x7fffu + ((u >> 16) & 1u)) >> 16;
    return (unsigned short)r;
}
__device__ inline float bf2f(unsigned short h) { return __uint_as_float(((unsigned)h) << 16); }

// ---------------- K1: degrees + norms + CSR (src+dst); blocks >= NG pack W ----------------
__global__ __launch_bounds__(1024) void k_build(const int* __restrict__ edges,
                                                float* __restrict__ rs_out,
                                                float* __restrict__ rs_in,
                                                int* __restrict__ row_ofs,
                                                int* __restrict__ csr_src,
                                                int* __restrict__ csr_dst,
                                                const float* __restrict__ W0,
                                                const float* __restrict__ W1,
                                                unsigned short* __restrict__ WP) {
    int g = blockIdx.x;
    int tid = threadIdx.x;

    if (g >= NG) {
        int which = g - NG;
        const float* W = which ? W1 : W0;
        for (int task = tid; task < 2048; task += 1024) {
            int t = task >> 6;            // 0..31  (nt*4+kk)
            int lane = task & 63;
            int nt = t >> 2, kk = t & 3;
            int n = nt * 16 + (lane & 15);
            int k0 = kk * 32 + (lane >> 4) * 8;
            unsigned short* dh = WP + ((size_t)which * 2 + 0) * 16384 + ((size_t)t * 64 + lane) * 8;
            unsigned short* dl = WP + ((size_t)which * 2 + 1) * 16384 + ((size_t)t * 64 + lane) * 8;
#pragma unroll
            for (int j = 0; j < 8; j++) {
                float v = W[(size_t)(k0 + j) * FH + n];
                unsigned short h = f2bf(v);
                dh[j] = h;
                dl[j] = f2bf(v - bf2f(h));
            }
        }
        return;
    }

    const int* src = edges + (size_t)g * 2 * NE;
    const int* dst = src + NE;

    __shared__ int degO[NN], degI[NN];
    __shared__ int scanA[NN], scanB[NN];
    __shared__ int fill[NN];
    __shared__ int csr_lds[NE];          // 32 KB
    __shared__ int dst_lds[NE];          // 32 KB

    for (int i = tid; i < NN; i += 1024) { degO[i] = 0; degI[i] = 0; }
    __syncthreads();
    for (int u = tid; u < NE / 4; u += 1024) {
        int4 s = ((const int4*)src)[u];
        int4 d = ((const int4*)dst)[u];
        atomicAdd(&degO[s.x], 1); atomicAdd(&degO[s.y], 1);
        atomicAdd(&degO[s.z], 1); atomicAdd(&degO[s.w], 1);
        atomicAdd(&degI[d.x], 1); atomicAdd(&degI[d.y], 1);
        atomicAdd(&degI[d.z], 1); atomicAdd(&degI[d.w], 1);
    }
    __syncthreads();
    for (int i = tid; i < NN; i += 1024) {
        int dO = degO[i], dI = degI[i];
        rs_out[g * NN + i] = rsqrtf((float)max(dO, 1));
        rs_in [g * NN + i] = rsqrtf((float)max(dI, 1));
        scanA[i] = dI;
    }
    __syncthreads();
    int* sA = scanA; int* sB = scanB;
    for (int off = 1; off < NN; off <<= 1) {
        for (int i = tid; i < NN; i += 1024) {
            int v = sA[i];
            if (i >= off) v += sA[i - off];
            sB[i] = v;
        }
        __syncthreads();
        int* t = sA; sA = sB; sB = t;
    }
    for (int i = tid; i < NN; i += 1024) {
        int excl = (i == 0) ? 0 : sA[i - 1];
        fill[i] = excl;
        row_ofs[g * 513 + i] = excl;
    }
    if (tid == 0) row_ofs[g * 513 + NN] = sA[NN - 1];
    __syncthreads();
    for (int u = tid; u < NE / 4; u += 1024) {
        int4 s = ((const int4*)src)[u];
        int4 d = ((const int4*)dst)[u];
        int p0 = atomicAdd(&fill[d.x], 1); csr_lds[p0] = s.x; dst_lds[p0] = d.x;
        int p1 = atomicAdd(&fill[d.y], 1); csr_lds[p1] = s.y; dst_lds[p1] = d.y;
        int p2 = atomicAdd(&fill[d.z], 1); csr_lds[p2] = s.z; dst_lds[p2] = d.z;
        int p3 = atomicAdd(&fill[d.w], 1); csr_lds[p3] = s.w; dst_lds[p3] = d.w;
    }
    __syncthreads();
    for (int u = tid; u < NE / 4; u += 1024) {
        ((int4*)(csr_src + (size_t)g * NE))[u] = ((const int4*)csr_lds)[u];
        ((int4*)(csr_dst + (size_t)g * NE))[u] = ((const int4*)dst_lds)[u];
    }
}

// ---------------- K2: Y1f = pack_Bfrag((feats @ W0) * rs)  (hi/lo split, 3 MFMA) ----------------
// Output written directly in MFMA B-fragment order:
// element (k,n) -> frag(kk=k>>5, nt=n>>4), lane=(n&15)|(((k>>3)&3)<<4), j=k&7.
__global__ __launch_bounds__(256) void k_gemm_f32(const float* __restrict__ X,
                                                  const unsigned short* __restrict__ WPh,
                                                  const unsigned short* __restrict__ WPl,
                                                  const float* __restrict__ rs,
                                                  unsigned short* __restrict__ Yf) {
    __shared__ unsigned short xh[64 * XPITCH];   // 17 KB
    __shared__ unsigned short xl[64 * XPITCH];   // 17 KB
    int tid = threadIdx.x;
    int sb = blockIdx.y;
    size_t r0 = (size_t)blockIdx.x * NN + (size_t)sb * 64;

    const float4* Xv = (const float4*)(X + r0 * FH);
#pragma unroll
    for (int i = 0; i < 8; i++) {
        int u = tid + i * 256;                 // 2048 float4 = 64x128
        int row = u >> 5, c4 = (u & 31) * 4;
        float4 v = Xv[u];
        int off = row * XPITCH + c4;
        unsigned short h0 = f2bf(v.x), h1 = f2bf(v.y), h2 = f2bf(v.z), h3 = f2bf(v.w);
        xh[off + 0] = h0; xh[off + 1] = h1; xh[off + 2] = h2; xh[off + 3] = h3;
        xl[off + 0] = f2bf(v.x - bf2f(h0));
        xl[off + 1] = f2bf(v.y - bf2f(h1));
        xl[off + 2] = f2bf(v.z - bf2f(h2));
        xl[off + 3] = f2bf(v.w - bf2f(h3));
    }
    __syncthreads();

    int lane = tid & 63, w = tid >> 6;
    int quad = lane >> 4, m = lane & 15;
    int arow = w * 16 + m;

    f4v acc[8];
#pragma unroll
    for (int nt = 0; nt < 8; nt++) acc[nt] = (f4v){0.f, 0.f, 0.f, 0.f};

#pragma unroll
    for (int kk = 0; kk < 4; kk++) {
        s8v ah = *(const s8v*)&xh[arow * XPITCH + kk * 32 + quad * 8];
        s8v al = *(const s8v*)&xl[arow * XPITCH + kk * 32 + quad * 8];
#pragma unroll
        for (int nt = 0; nt < 8; nt++) {
            s8v bh = *(const s8v*)(WPh + ((size_t)(nt * 4 + kk) * 64 + lane) * 8);
            s8v bl = *(const s8v*)(WPl + ((size_t)(nt * 4 + kk) * 64 + lane) * 8);
            acc[nt] = __builtin_amdgcn_mfma_f32_16x16x32_bf16(ah, bh, acc[nt], 0, 0, 0);
            acc[nt] = __builtin_amdgcn_mfma_f32_16x16x32_bf16(al, bh, acc[nt], 0, 0, 0);
            acc[nt] = __builtin_amdgcn_mfma_f32_16x16x32_bf16(ah, bl, acc[nt], 0, 0, 0);
        }
    }

    int orow = w * 16 + quad * 4;
    float4 rsv = *(const float4*)(rs + r0 + orow);
    int tag = (w * 2 + (quad >> 1)) & 3;
    int kko = sb * 2 + (w >> 1);
    int j0  = (quad & 1) * 4;
    unsigned short* of = Yf + (size_t)blockIdx.x * (NN * FH);
#pragma unroll
    for (int nt = 0; nt < 8; nt++) {
        us4v v;
        v.x = f2bf(acc[nt][0] * rsv.x);
        v.y = f2bf(acc[nt][1] * rsv.y);
        v.z = f2bf(acc[nt][2] * rsv.z);
        v.w = f2bf(acc[nt][3] * rsv.w);
        *(us4v*)(of + (((size_t)kko * 8 + nt) * 64 + (m + 16 * tag)) * 8 + j0) = v;
    }
}

// ---------------- K3: FUSED dense-A MFMA aggregation (conv1) + bf16 MFMA gemm2 -> Y2f ----------------
// Block (g, sb): D[64x128] = A_slab[64x512] @ Y1[512x128] via 4 src-chunks of 128.
// A built as int in LDS (native int atomics, exact w/ duplicate edges); hs aliases A.
__global__ __launch_bounds__(512) void k_fused(const unsigned short* __restrict__ Y1f,
                                               const int* __restrict__ row_ofs,
                                               const int* __restrict__ csr_src,
                                               const int* __restrict__ csr_dst,
                                               const float* __restrict__ rs_in,
                                               const float* __restrict__ rs_out,
                                               const float* __restrict__ bias,
                                               const unsigned short* __restrict__ WPh,
                                               const unsigned short* __restrict__ WPl,
                                               unsigned short* __restrict__ Y2f) {
    int g  = blockIdx.x;
    int sb = blockIdx.y;   // 0..7
    int tid = threadIdx.x;
    int lane = tid & 63, w8 = tid >> 6;    // 8 waves
    int quad = lane >> 4, m = lane & 15;
    int mt = w8 & 3, nh = w8 >> 2;
    int base = sb * 64;

    __shared__ int Ach[64 * APITCH];       // 33792 B; hs aliases this after agg
    unsigned short* hs = (unsigned short*)Ach;
    __shared__ float rsin_s[64];

    if (tid < 64) rsin_s[tid] = rs_in[g * NN + base + tid];

    int eS = row_ofs[g * 513 + base];
    int eE = row_ofs[g * 513 + base + 64];
    const int* cs = csr_src + (size_t)g * NE;
    const int* cd = csr_dst + (size_t)g * NE;
    const unsigned short* Yf = Y1f + (size_t)g * (NN * FH);

    f4v acc[4];
#pragma unroll
    for (int j = 0; j < 4; j++) acc[j] = (f4v){0.f, 0.f, 0.f, 0.f};

    for (int p = 0; p < 4; p++) {
        __syncthreads();                    // prior chunk's A reads done
        for (int i = tid; i < 64 * APITCH; i += 512) Ach[i] = 0;
        __syncthreads();
        for (int e = eS + tid; e < eE; e += 512) {
            int s = cs[e], d = cd[e];
            if ((s >> 7) == p) atomicAdd(&Ach[(d - base) * APITCH + (s & 127)], 1);
        }
        __syncthreads();
#pragma unroll
        for (int kkl = 0; kkl < 4; kkl++) {
            int kk = p * 4 + kkl;
            s8v bf[4];
#pragma unroll
            for (int j = 0; j < 4; j++)
                bf[j] = *(const s8v*)(Yf + (((size_t)kk * 8 + (nh * 4 + j)) * 64 + lane) * 8);
            int arow = mt * 16 + m;
            int k0 = quad * 8 + kkl * 32;
            const int* ap = &Ach[arow * APITCH + k0];
            int4 a0 = *(const int4*)ap;
            int4 a1 = *(const int4*)(ap + 4);
            s8v af;
            af[0] = (short)f2bf((float)a0.x); af[1] = (short)f2bf((float)a0.y);
            af[2] = (short)f2bf((float)a0.z); af[3] = (short)f2bf((float)a0.w);
            af[4] = (short)f2bf((float)a1.x); af[5] = (short)f2bf((float)a1.y);
            af[6] = (short)f2bf((float)a1.z); af[7] = (short)f2bf((float)a1.w);
#pragma unroll
            for (int j = 0; j < 4; j++)
                acc[j] = __builtin_amdgcn_mfma_f32_16x16x32_bf16(af, bf[j], acc[j], 0, 0, 0);
        }
    }
    __syncthreads();   // agg done; Ach reusable as hs

    // ---- conv1 epilogue: h = relu(rs_in*agg + b0) -> hs (natural [row][feat]) ----
#pragma unroll
    for (int j = 0; j < 4; j++) {
        int feat = (nh * 4 + j) * 16 + m;
        float bv = bias[feat];
#pragma unroll
        for (int i = 0; i < 4; i++) {
            int r = mt * 16 + quad * 4 + i;
            float hv = fmaxf(fmaf(rsin_s[r], acc[j][i], bv), 0.f);
            hs[r * XPITCH + feat] = f2bf(hv);
        }
    }
    __syncthreads();

    // ---- gemm2: Y2 = (h @ W1) * rs_out, packed B-fragment output ----
    f4v acc2[4];
#pragma unroll
    for (int j = 0; j < 4; j++) acc2[j] = (f4v){0.f, 0.f, 0.f, 0.f};

#pragma unroll
    for (int kk = 0; kk < 4; kk++) {
        s8v ah = *(const s8v*)&hs[(mt * 16 + m) * XPITCH + kk * 32 + quad * 8];
#pragma unroll
        for (int j = 0; j < 4; j++) {
            int nt = nh * 4 + j;
            s8v bh = *(const s8v*)(WPh + ((size_t)(nt * 4 + kk) * 64 + lane) * 8);
            s8v bl = *(const s8v*)(WPl + ((size_t)(nt * 4 + kk) * 64 + lane) * 8);
            acc2[j] = __builtin_amdgcn_mfma_f32_16x16x32_bf16(ah, bh, acc2[j], 0, 0, 0);
            acc2[j] = __builtin_amdgcn_mfma_f32_16x16x32_bf16(ah, bl, acc2[j], 0, 0, 0);
        }
    }

    int orow = mt * 16 + quad * 4;
    float4 rsv = *(const float4*)(rs_out + (size_t)g * NN + base + orow);
    int tag = (mt * 2 + (quad >> 1)) & 3;
    int kko = sb * 2 + (mt >> 1);
    int j0  = (quad & 1) * 4;
    unsigned short* of = Y2f + (size_t)g * (NN * FH);
#pragma unroll
    for (int j = 0; j < 4; j++) {
        int nt = nh * 4 + j;
        us4v v;
        v.x = f2bf(acc2[j][0] * rsv.x);
        v.y = f2bf(acc2[j][1] * rsv.y);
        v.z = f2bf(acc2[j][2] * rsv.z);
        v.w = f2bf(acc2[j][3] * rsv.w);
        *(us4v*)(of + (((size_t)kko * 8 + nt) * 64 + (m + 16 * tag)) * 8 + j0) = v;
    }
}

// ---------------- K4: dense-A MFMA aggregation (conv2) + relu + node-sum -> partial[g][sb] ----------------
__global__ __launch_bounds__(512) void k_gather_mean(const unsigned short* __restrict__ Y2f,
                                                     const int* __restrict__ row_ofs,
                                                     const int* __restrict__ csr_src,
                                                     const int* __restrict__ csr_dst,
                                                     const float* __restrict__ rs_in,
                                                     const float* __restrict__ bias,
                                                     float* __restrict__ partial) {
    int g  = blockIdx.x;
    int sb = blockIdx.y;
    int tid = threadIdx.x;
    int lane = tid & 63, w8 = tid >> 6;
    int quad = lane >> 4, m = lane & 15;
    int mt = w8 & 3, nh = w8 >> 2;
    int base = sb * 64;

    __shared__ int Ach[64 * APITCH];            // 33792 B; red aliases this after agg
    float* red = (float*)Ach;                   // [8][64][4]
    __shared__ float rsin_s[64];

    if (tid < 64) rsin_s[tid] = rs_in[g * NN + base + tid];

    int eS = row_ofs[g * 513 + base];
    int eE = row_ofs[g * 513 + base + 64];
    const int* cs = csr_src + (size_t)g * NE;
    const int* cd = csr_dst + (size_t)g * NE;
    const unsigned short* Yf = Y2f + (size_t)g * (NN * FH);

    f4v acc[4];
#pragma unroll
    for (int j = 0; j < 4; j++) acc[j] = (f4v){0.f, 0.f, 0.f, 0.f};

    for (int p = 0; p < 4; p++) {
        __syncthreads();
        for (int i = tid; i < 64 * APITCH; i += 512) Ach[i] = 0;
        __syncthreads();
        for (int e = eS + tid; e < eE; e += 512) {
            int s = cs[e], d = cd[e];
            if ((s >> 7) == p) atomicAdd(&Ach[(d - base) * APITCH + (s & 127)], 1);
        }
        __syncthreads();
#pragma unroll
        for (int kkl = 0; kkl < 4; kkl++) {
            int kk = p * 4 + kkl;
            s8v bf[4];
#pragma unroll
            for (int j = 0; j < 4; j++)
                bf[j] = *(const s8v*)(Yf + (((size_t)kk * 8 + (nh * 4 + j)) * 64 + lane) * 8);
            int arow = mt * 16 + m;
            int k0 = quad * 8 + kkl * 32;
            const int* ap = &Ach[arow * APITCH + k0];
            int4 a0 = *(const int4*)ap;
            int4 a1 = *(const int4*)(ap + 4);
            s8v af;
            af[0] = (short)f2bf((float)a0.x); af[1] = (short)f2bf((float)a0.y);
            af[2] = (short)f2bf((float)a0.z); af[3] = (short)f2bf((float)a0.w);
            af[4] = (short)f2bf((float)a1.x); af[5] = (short)f2bf((float)a1.y);
            af[6] = (short)f2bf((float)a1.z); af[7] = (short)f2bf((float)a1.w);
#pragma unroll
            for (int j = 0; j < 4; j++)
                acc[j] = __builtin_amdgcn_mfma_f32_16x16x32_bf16(af, bf[j], acc[j], 0, 0, 0);
        }
    }
    __syncthreads();   // agg done; Ach reusable as red

    // ---- epilogue: relu(rs_in*agg + b1) summed over this lane's 4 rows, per nt ----
#pragma unroll
    for (int j = 0; j < 4; j++) {
        int feat = (nh * 4 + j) * 16 + m;
        float bv = bias[feat];
        float s = 0.f;
#pragma unroll
        for (int i = 0; i < 4; i++) {
            int r = mt * 16 + quad * 4 + i;
            s += fmaxf(fmaf(rsin_s[r], acc[j][i], bv), 0.f);
        }
        red[(w8 * 64 + lane) * 4 + j] = s;
    }
    __syncthreads();
    if (tid < FH) {
        int f = tid;
        int nt = f >> 4, mm = f & 15;
        int nhh = nt >> 2, jj = nt & 3;
        float t = 0.f;
#pragma unroll
        for (int mtt = 0; mtt < 4; mtt++)
#pragma unroll
            for (int q = 0; q < 4; q++)
                t += red[(((nhh * 4 + mtt) * 64) + q * 16 + mm) * 4 + jj];
        partial[((size_t)g * 8 + sb) * FH + f] = t;
    }
}

// ---------------- K5: z = (sum partials)/512 @ Wt + bt; BN eval; relu ----------------
__global__ __launch_bounds__(128) void k_head(const float* __restrict__ partial,
                                              const float* __restrict__ Wt,
                                              const float* __restrict__ bt,
                                              const float* __restrict__ gamma,
                                              const float* __restrict__ beta,
                                              const float* __restrict__ rmean,
                                              const float* __restrict__ rvar,
                                              float* __restrict__ out) {
    int g = blockIdx.x;
    int j = threadIdx.x;
    __shared__ float e[FH];
    float acc8 = 0.f;
#pragma unroll
    for (int q = 0; q < 8; q++) acc8 += partial[((size_t)g * 8 + q) * FH + j];
    e[j] = acc8 * (1.0f / (float)NN);
    __syncthreads();
    float acc = bt[j];
#pragma unroll 8
    for (int k = 0; k < FH; k++) acc += e[k] * Wt[(size_t)k * FH + j];
    float z = gamma[j] * (acc - rmean[j]) * rsqrtf(rvar[j] + BN_EPS) + beta[j];
    out[g * FH + j] = fmaxf(z, 0.f);
}

extern "C" void kernel_launch(void* const* d_in, const int* in_sizes, int n_in,
                              void* d_out, int out_size, void* d_ws, size_t ws_size,
                              hipStream_t stream) {
    const float* feats = (const float*)d_in[0];
    const int*   edges = (const int*)d_in[1];
    const float* W0    = (const float*)d_in[2];
    const float* b0    = (const float*)d_in[3];
    const float* W1    = (const float*)d_in[4];
    const float* b1    = (const float*)d_in[5];
    const float* Wt    = (const float*)d_in[6];
    const float* bt    = (const float*)d_in[7];
    const float* gamma = (const float*)d_in[8];
    const float* beta  = (const float*)d_in[9];
    const float* rmean = (const float*)d_in[10];
    const float* rvar  = (const float*)d_in[11];
    float* out = (float*)d_out;

    // workspace layout
    char* w = (char*)d_ws;
    float* rs_out  = (float*)w;   w += sizeof(float) * NG * NN;
    float* rs_in   = (float*)w;   w += sizeof(float) * NG * NN;
    int*   row_ofs = (int*)w;     w += sizeof(int) * NG * 520;
    int*   csr_src = (int*)w;     w += sizeof(int) * ((size_t)NG * NE + 16);
    int*   csr_dst = (int*)w;     w += sizeof(int) * ((size_t)NG * NE + 16);
    unsigned short* WP = (unsigned short*)w;  w += sizeof(unsigned short) * 4 * 16384; // 128 KB
    unsigned short* Y1 = (unsigned short*)w;  w += sizeof(unsigned short) * (size_t)NG * NN * FH; // 16 MB
    unsigned short* Y2 = (unsigned short*)w;  w += sizeof(unsigned short) * (size_t)NG * NN * FH; // 16 MB
    float* partial = (float*)w;   w += sizeof(float) * NG * 8 * FH;

    unsigned short* WPh0 = WP;
    unsigned short* WPl0 = WP + 16384;
    unsigned short* WPh1 = WP + 32768;
    unsigned short* WPl1 = WP + 49152;

    // K1: build norms + CSR; 2 extra blocks pack W0/W1
    k_build<<<NG + 2, 1024, 0, stream>>>(edges, rs_out, rs_in, row_ofs, csr_src, csr_dst,
                                         W0, W1, WP);

    // K2: conv1 gemm (feats -> Y1, B-fragment packed), XCD = g%8
    k_gemm_f32<<<dim3(NG, 8), 256, 0, stream>>>(feats, WPh0, WPl0, rs_out, Y1);

    // K3: fused dense-A MFMA aggregation + conv2 gemm (Y1 -> Y2, packed)
    k_fused<<<dim3(NG, 8), 512, 0, stream>>>(Y1, row_ofs, csr_src, csr_dst,
                                             rs_in, rs_out, b0, WPh1, WPl1, Y2);

    // K4: dense-A MFMA aggregation (conv2) + node-mean partials
    k_gather_mean<<<dim3(NG, 8), 512, 0, stream>>>(Y2, row_ofs, csr_src, csr_dst, rs_in, b1, partial);

    // K5: head
    k_head<<<NG, 128, 0, stream>>>(partial, Wt, bt, gamma, beta, rmean, rvar, out);

    (void)in_sizes; (void)n_in; (void)out_size; (void)ws_size;
}

// Round 17
// 183.652 us; speedup vs baseline: 8.1510x; 1.0405x over previous
//
#include <hip/hip_runtime.h>
#include <hip/hip_bf16.h>

#define NN 512      // nodes per graph
#define NE 8192     // edges per graph
#define NG 128      // graphs (B*G)
#define FH 128      // feature/hidden dim
#define APITCH 68   // A-chunk int pitch: 272 B row (16B-aligned), bank stride 4 -> 2-way (free)
#define XPITCH 136
#define BN_EPS 1e-5f

typedef __attribute__((ext_vector_type(8))) short s8v;            // 8 bf16 = 4 VGPRs
typedef __attribute__((ext_vector_type(4))) float f4v;            // MFMA C/D
typedef __attribute__((ext_vector_type(4))) unsigned short us4v;  // native ushort4

__device__ inline unsigned short f2bf(float x) {   // RNE fp32 -> bf16 bits
    unsigned u = __float_as_uint(x);
    unsigned r = (u + 0x7fffu + ((u >> 16) & 1u)) >> 16;
    return (unsigned short)r;
}
__device__ inline float bf2f(unsigned short h) { return __uint_as_float(((unsigned)h) << 16); }

// ---------------- K1: degrees + norms + CSR (src+dst); blocks >= NG pack W ----------------
__global__ __launch_bounds__(1024) void k_build(const int* __restrict__ edges,
                                                float* __restrict__ rs_out,
                                                float* __restrict__ rs_in,
                                                int* __restrict__ row_ofs,
                                                int* __restrict__ csr_src,
                                                int* __restrict__ csr_dst,
                                                const float* __restrict__ W0,
                                                const float* __restrict__ W1,
                                                unsigned short* __restrict__ WP) {
    int g = blockIdx.x;
    int tid = threadIdx.x;

    if (g >= NG) {
        int which = g - NG;
        const float* W = which ? W1 : W0;
        for (int task = tid; task < 2048; task += 1024) {
            int t = task >> 6;            // 0..31  (nt*4+kk)
            int lane = task & 63;
            int nt = t >> 2, kk = t & 3;
            int n = nt * 16 + (lane & 15);
            int k0 = kk * 32 + (lane >> 4) * 8;
            unsigned short* dh = WP + ((size_t)which * 2 + 0) * 16384 + ((size_t)t * 64 + lane) * 8;
            unsigned short* dl = WP + ((size_t)which * 2 + 1) * 16384 + ((size_t)t * 64 + lane) * 8;
#pragma unroll
            for (int j = 0; j < 8; j++) {
                float v = W[(size_t)(k0 + j) * FH + n];
                unsigned short h = f2bf(v);
                dh[j] = h;
                dl[j] = f2bf(v - bf2f(h));
            }
        }
        return;
    }

    const int* src = edges + (size_t)g * 2 * NE;
    const int* dst = src + NE;

    __shared__ int degO[NN], degI[NN];
    __shared__ int scanA[NN], scanB[NN];
    __shared__ int fill[NN];
    __shared__ int csr_lds[NE];          // 32 KB
    __shared__ int dst_lds[NE];          // 32 KB

    for (int i = tid; i < NN; i += 1024) { degO[i] = 0; degI[i] = 0; }
    __syncthreads();
    for (int u = tid; u < NE / 4; u += 1024) {
        int4 s = ((const int4*)src)[u];
        int4 d = ((const int4*)dst)[u];
        atomicAdd(&degO[s.x], 1); atomicAdd(&degO[s.y], 1);
        atomicAdd(&degO[s.z], 1); atomicAdd(&degO[s.w], 1);
        atomicAdd(&degI[d.x], 1); atomicAdd(&degI[d.y], 1);
        atomicAdd(&degI[d.z], 1); atomicAdd(&degI[d.w], 1);
    }
    __syncthreads();
    for (int i = tid; i < NN; i += 1024) {
        int dO = degO[i], dI = degI[i];
        rs_out[g * NN + i] = rsqrtf((float)max(dO, 1));
        rs_in [g * NN + i] = rsqrtf((float)max(dI, 1));
        scanA[i] = dI;
    }
    __syncthreads();
    int* sA = scanA; int* sB = scanB;
    for (int off = 1; off < NN; off <<= 1) {
        for (int i = tid; i < NN; i += 1024) {
            int v = sA[i];
            if (i >= off) v += sA[i - off];
            sB[i] = v;
        }
        __syncthreads();
        int* t = sA; sA = sB; sB = t;
    }
    for (int i = tid; i < NN; i += 1024) {
        int excl = (i == 0) ? 0 : sA[i - 1];
        fill[i] = excl;
        row_ofs[g * 513 + i] = excl;
    }
    if (tid == 0) row_ofs[g * 513 + NN] = sA[NN - 1];
    __syncthreads();
    for (int u = tid; u < NE / 4; u += 1024) {
        int4 s = ((const int4*)src)[u];
        int4 d = ((const int4*)dst)[u];
        int p0 = atomicAdd(&fill[d.x], 1); csr_lds[p0] = s.x; dst_lds[p0] = d.x;
        int p1 = atomicAdd(&fill[d.y], 1); csr_lds[p1] = s.y; dst_lds[p1] = d.y;
        int p2 = atomicAdd(&fill[d.z], 1); csr_lds[p2] = s.z; dst_lds[p2] = d.z;
        int p3 = atomicAdd(&fill[d.w], 1); csr_lds[p3] = s.w; dst_lds[p3] = d.w;
    }
    __syncthreads();
    for (int u = tid; u < NE / 4; u += 1024) {
        ((int4*)(csr_src + (size_t)g * NE))[u] = ((const int4*)csr_lds)[u];
        ((int4*)(csr_dst + (size_t)g * NE))[u] = ((const int4*)dst_lds)[u];
    }
}

// ---------------- K2: Y1f = pack_Bfrag((feats @ W0) * rs)  (hi/lo split, 3 MFMA) ----------------
__global__ __launch_bounds__(256) void k_gemm_f32(const float* __restrict__ X,
                                                  const unsigned short* __restrict__ WPh,
                                                  const unsigned short* __restrict__ WPl,
                                                  const float* __restrict__ rs,
                                                  unsigned short* __restrict__ Yf) {
    __shared__ unsigned short xh[64 * XPITCH];   // 17 KB
    __shared__ unsigned short xl[64 * XPITCH];   // 17 KB
    int tid = threadIdx.x;
    int sb = blockIdx.y;
    size_t r0 = (size_t)blockIdx.x * NN + (size_t)sb * 64;

    const float4* Xv = (const float4*)(X + r0 * FH);
#pragma unroll
    for (int i = 0; i < 8; i++) {
        int u = tid + i * 256;                 // 2048 float4 = 64x128
        int row = u >> 5, c4 = (u & 31) * 4;
        float4 v = Xv[u];
        int off = row * XPITCH + c4;
        unsigned short h0 = f2bf(v.x), h1 = f2bf(v.y), h2 = f2bf(v.z), h3 = f2bf(v.w);
        xh[off + 0] = h0; xh[off + 1] = h1; xh[off + 2] = h2; xh[off + 3] = h3;
        xl[off + 0] = f2bf(v.x - bf2f(h0));
        xl[off + 1] = f2bf(v.y - bf2f(h1));
        xl[off + 2] = f2bf(v.z - bf2f(h2));
        xl[off + 3] = f2bf(v.w - bf2f(h3));
    }
    __syncthreads();

    int lane = tid & 63, w = tid >> 6;
    int quad = lane >> 4, m = lane & 15;
    int arow = w * 16 + m;

    f4v acc[8];
#pragma unroll
    for (int nt = 0; nt < 8; nt++) acc[nt] = (f4v){0.f, 0.f, 0.f, 0.f};

#pragma unroll
    for (int kk = 0; kk < 4; kk++) {
        s8v ah = *(const s8v*)&xh[arow * XPITCH + kk * 32 + quad * 8];
        s8v al = *(const s8v*)&xl[arow * XPITCH + kk * 32 + quad * 8];
#pragma unroll
        for (int nt = 0; nt < 8; nt++) {
            s8v bh = *(const s8v*)(WPh + ((size_t)(nt * 4 + kk) * 64 + lane) * 8);
            s8v bl = *(const s8v*)(WPl + ((size_t)(nt * 4 + kk) * 64 + lane) * 8);
            acc[nt] = __builtin_amdgcn_mfma_f32_16x16x32_bf16(ah, bh, acc[nt], 0, 0, 0);
            acc[nt] = __builtin_amdgcn_mfma_f32_16x16x32_bf16(al, bh, acc[nt], 0, 0, 0);
            acc[nt] = __builtin_amdgcn_mfma_f32_16x16x32_bf16(ah, bl, acc[nt], 0, 0, 0);
        }
    }

    int orow = w * 16 + quad * 4;
    float4 rsv = *(const float4*)(rs + r0 + orow);
    int tag = (w * 2 + (quad >> 1)) & 3;
    int kko = sb * 2 + (w >> 1);
    int j0  = (quad & 1) * 4;
    unsigned short* of = Yf + (size_t)blockIdx.x * (NN * FH);
#pragma unroll
    for (int nt = 0; nt < 8; nt++) {
        us4v v;
        v.x = f2bf(acc[nt][0] * rsv.x);
        v.y = f2bf(acc[nt][1] * rsv.y);
        v.z = f2bf(acc[nt][2] * rsv.z);
        v.w = f2bf(acc[nt][3] * rsv.w);
        *(us4v*)(of + (((size_t)kko * 8 + nt) * 64 + (m + 16 * tag)) * 8 + j0) = v;
    }
}

// ---------------- K3: FUSED dense-A MFMA aggregation (LDS-staged B) + bf16 MFMA gemm2 -> Y2f ----------------
// Block (g, sb): D[64x128] = A_slab[64x512] @ Y1[512x128] via 8 src-chunks of 64.
// Per pass: A-chunk via native int LDS atomics; B-chunk (16 KB) staged once into LDS
// and shared by all 8 waves (kills the 4x per-wave L2 re-read that capped R16 at 42 us).
__global__ __launch_bounds__(512) void k_fused(const unsigned short* __restrict__ Y1f,
                                               const int* __restrict__ row_ofs,
                                               const int* __restrict__ csr_src,
                                               const int* __restrict__ csr_dst,
                                               const float* __restrict__ rs_in,
                                               const float* __restrict__ rs_out,
                                               const float* __restrict__ bias,
                                               const unsigned short* __restrict__ WPh,
                                               const unsigned short* __restrict__ WPl,
                                               unsigned short* __restrict__ Y2f) {
    int g  = blockIdx.x;
    int sb = blockIdx.y;   // 0..7
    int tid = threadIdx.x;
    int lane = tid & 63, w8 = tid >> 6;    // 8 waves
    int quad = lane >> 4, m = lane & 15;
    int mt = w8 & 3, nh = w8 >> 2;
    int base = sb * 64;

    __shared__ int Ach[64 * APITCH];             // 17408 B; hs aliases this after agg
    __shared__ unsigned short Bs[2 * 8 * 64 * 8]; // 16384 B B-chunk
    unsigned short* hs = (unsigned short*)Ach;    // 64*XPITCH*2 = 17408 B exactly
    __shared__ float rsin_s[64];

    if (tid < 64) rsin_s[tid] = rs_in[g * NN + base + tid];

    int eS = row_ofs[g * 513 + base];
    int eE = row_ofs[g * 513 + base + 64];
    const int* cs = csr_src + (size_t)g * NE;
    const int* cd = csr_dst + (size_t)g * NE;
    const int4* Yi4 = (const int4*)(Y1f + (size_t)g * (NN * FH));
    int4* Bi4 = (int4*)Bs;

    f4v acc[4];
#pragma unroll
    for (int j = 0; j < 4; j++) acc[j] = (f4v){0.f, 0.f, 0.f, 0.f};

    for (int p = 0; p < 8; p++) {
        __syncthreads();                    // prior pass's A/B reads done
        for (int i = tid; i < 64 * APITCH; i += 512) Ach[i] = 0;
        __syncthreads();
        for (int e = eS + tid; e < eE; e += 512) {
            int s = cs[e], d = cd[e];
            if ((s >> 6) == p) atomicAdd(&Ach[(d - base) * APITCH + (s & 63)], 1);
        }
        // stage B-chunk: fragments kk = 2p, 2p+1 (1024 int4, coalesced)
        for (int u = tid; u < 1024; u += 512) Bi4[u] = Yi4[p * 1024 + u];
        __syncthreads();
#pragma unroll
        for (int kkl = 0; kkl < 2; kkl++) {
            s8v bf[4];
#pragma unroll
            for (int j = 0; j < 4; j++)
                bf[j] = *(const s8v*)&Bs[((kkl * 8 + nh * 4 + j) * 64 + lane) * 8];
            const int* ap = &Ach[(mt * 16 + m) * APITCH + kkl * 32 + quad * 8];
            int4 a0 = *(const int4*)ap;
            int4 a1 = *(const int4*)(ap + 4);
            s8v af;
            af[0] = (short)f2bf((float)a0.x); af[1] = (short)f2bf((float)a0.y);
            af[2] = (short)f2bf((float)a0.z); af[3] = (short)f2bf((float)a0.w);
            af[4] = (short)f2bf((float)a1.x); af[5] = (short)f2bf((float)a1.y);
            af[6] = (short)f2bf((float)a1.z); af[7] = (short)f2bf((float)a1.w);
#pragma unroll
            for (int j = 0; j < 4; j++)
                acc[j] = __builtin_amdgcn_mfma_f32_16x16x32_bf16(af, bf[j], acc[j], 0, 0, 0);
        }
    }
    __syncthreads();   // agg done; Ach reusable as hs

    // ---- conv1 epilogue: h = relu(rs_in*agg + b0) -> hs (natural [row][feat]) ----
#pragma unroll
    for (int j = 0; j < 4; j++) {
        int feat = (nh * 4 + j) * 16 + m;
        float bv = bias[feat];
#pragma unroll
        for (int i = 0; i < 4; i++) {
            int r = mt * 16 + quad * 4 + i;
            float hv = fmaxf(fmaf(rsin_s[r], acc[j][i], bv), 0.f);
            hs[r * XPITCH + feat] = f2bf(hv);
        }
    }
    __syncthreads();

    // ---- gemm2: Y2 = (h @ W1) * rs_out, packed B-fragment output ----
    f4v acc2[4];
#pragma unroll
    for (int j = 0; j < 4; j++) acc2[j] = (f4v){0.f, 0.f, 0.f, 0.f};

#pragma unroll
    for (int kk = 0; kk < 4; kk++) {
        s8v ah = *(const s8v*)&hs[(mt * 16 + m) * XPITCH + kk * 32 + quad * 8];
#pragma unroll
        for (int j = 0; j < 4; j++) {
            int nt = nh * 4 + j;
            s8v bh = *(const s8v*)(WPh + ((size_t)(nt * 4 + kk) * 64 + lane) * 8);
            s8v bl = *(const s8v*)(WPl + ((size_t)(nt * 4 + kk) * 64 + lane) * 8);
            acc2[j] = __builtin_amdgcn_mfma_f32_16x16x32_bf16(ah, bh, acc2[j], 0, 0, 0);
            acc2[j] = __builtin_amdgcn_mfma_f32_16x16x32_bf16(ah, bl, acc2[j], 0, 0, 0);
        }
    }

    int orow = mt * 16 + quad * 4;
    float4 rsv = *(const float4*)(rs_out + (size_t)g * NN + base + orow);
    int tag = (mt * 2 + (quad >> 1)) & 3;
    int kko = sb * 2 + (mt >> 1);
    int j0  = (quad & 1) * 4;
    unsigned short* of = Y2f + (size_t)g * (NN * FH);
#pragma unroll
    for (int j = 0; j < 4; j++) {
        int nt = nh * 4 + j;
        us4v v;
        v.x = f2bf(acc2[j][0] * rsv.x);
        v.y = f2bf(acc2[j][1] * rsv.y);
        v.z = f2bf(acc2[j][2] * rsv.z);
        v.w = f2bf(acc2[j][3] * rsv.w);
        *(us4v*)(of + (((size_t)kko * 8 + nt) * 64 + (m + 16 * tag)) * 8 + j0) = v;
    }
}

// ---------------- K4: dense-A MFMA aggregation (LDS-staged B) + relu + node-sum -> partial ----------------
__global__ __launch_bounds__(512) void k_gather_mean(const unsigned short* __restrict__ Y2f,
                                                     const int* __restrict__ row_ofs,
                                                     const int* __restrict__ csr_src,
                                                     const int* __restrict__ csr_dst,
                                                     const float* __restrict__ rs_in,
                                                     const float* __restrict__ bias,
                                                     float* __restrict__ partial) {
    int g  = blockIdx.x;
    int sb = blockIdx.y;
    int tid = threadIdx.x;
    int lane = tid & 63, w8 = tid >> 6;
    int quad = lane >> 4, m = lane & 15;
    int mt = w8 & 3, nh = w8 >> 2;
    int base = sb * 64;

    __shared__ int Ach[64 * APITCH];              // 17408 B; red aliases this after agg
    __shared__ unsigned short Bs[2 * 8 * 64 * 8]; // 16384 B
    float* red = (float*)Ach;                     // [8][64][4] = 8192 B
    __shared__ float rsin_s[64];

    if (tid < 64) rsin_s[tid] = rs_in[g * NN + base + tid];

    int eS = row_ofs[g * 513 + base];
    int eE = row_ofs[g * 513 + base + 64];
    const int* cs = csr_src + (size_t)g * NE;
    const int* cd = csr_dst + (size_t)g * NE;
    const int4* Yi4 = (const int4*)(Y2f + (size_t)g * (NN * FH));
    int4* Bi4 = (int4*)Bs;

    f4v acc[4];
#pragma unroll
    for (int j = 0; j < 4; j++) acc[j] = (f4v){0.f, 0.f, 0.f, 0.f};

    for (int p = 0; p < 8; p++) {
        __syncthreads();
        for (int i = tid; i < 64 * APITCH; i += 512) Ach[i] = 0;
        __syncthreads();
        for (int e = eS + tid; e < eE; e += 512) {
            int s = cs[e], d = cd[e];
            if ((s >> 6) == p) atomicAdd(&Ach[(d - base) * APITCH + (s & 63)], 1);
        }
        for (int u = tid; u < 1024; u += 512) Bi4[u] = Yi4[p * 1024 + u];
        __syncthreads();
#pragma unroll
        for (int kkl = 0; kkl < 2; kkl++) {
            s8v bf[4];
#pragma unroll
            for (int j = 0; j < 4; j++)
                bf[j] = *(const s8v*)&Bs[((kkl * 8 + nh * 4 + j) * 64 + lane) * 8];
            const int* ap = &Ach[(mt * 16 + m) * APITCH + kkl * 32 + quad * 8];
            int4 a0 = *(const int4*)ap;
            int4 a1 = *(const int4*)(ap + 4);
            s8v af;
            af[0] = (short)f2bf((float)a0.x); af[1] = (short)f2bf((float)a0.y);
            af[2] = (short)f2bf((float)a0.z); af[3] = (short)f2bf((float)a0.w);
            af[4] = (short)f2bf((float)a1.x); af[5] = (short)f2bf((float)a1.y);
            af[6] = (short)f2bf((float)a1.z); af[7] = (short)f2bf((float)a1.w);
#pragma unroll
            for (int j = 0; j < 4; j++)
                acc[j] = __builtin_amdgcn_mfma_f32_16x16x32_bf16(af, bf[j], acc[j], 0, 0, 0);
        }
    }
    __syncthreads();   // agg done; Ach reusable as red

    // ---- epilogue: relu(rs_in*agg + b1) summed over this lane's 4 rows, per nt ----
#pragma unroll
    for (int j = 0; j < 4; j++) {
        int feat = (nh * 4 + j) * 16 + m;
        float bv = bias[feat];
        float s = 0.f;
#pragma unroll
        for (int i = 0; i < 4; i++) {
            int r = mt * 16 + quad * 4 + i;
            s += fmaxf(fmaf(rsin_s[r], acc[j][i], bv), 0.f);
        }
        red[(w8 * 64 + lane) * 4 + j] = s;
    }
    __syncthreads();
    if (tid < FH) {
        int f = tid;
        int nt = f >> 4, mm = f & 15;
        int nhh = nt >> 2, jj = nt & 3;
        float t = 0.f;
#pragma unroll
        for (int mtt = 0; mtt < 4; mtt++)
#pragma unroll
            for (int q = 0; q < 4; q++)
                t += red[(((nhh * 4 + mtt) * 64) + q * 16 + mm) * 4 + jj];
        partial[((size_t)g * 8 + sb) * FH + f] = t;
    }
}

// ---------------- K5: z = (sum partials)/512 @ Wt + bt; BN eval; relu ----------------
__global__ __launch_bounds__(128) void k_head(const float* __restrict__ partial,
                                              const float* __restrict__ Wt,
                                              const float* __restrict__ bt,
                                              const float* __restrict__ gamma,
                                              const float* __restrict__ beta,
                                              const float* __restrict__ rmean,
                                              const float* __restrict__ rvar,
                                              float* __restrict__ out) {
    int g = blockIdx.x;
    int j = threadIdx.x;
    __shared__ float e[FH];
    float acc8 = 0.f;
#pragma unroll
    for (int q = 0; q < 8; q++) acc8 += partial[((size_t)g * 8 + q) * FH + j];
    e[j] = acc8 * (1.0f / (float)NN);
    __syncthreads();
    float acc = bt[j];
#pragma unroll 8
    for (int k = 0; k < FH; k++) acc += e[k] * Wt[(size_t)k * FH + j];
    float z = gamma[j] * (acc - rmean[j]) * rsqrtf(rvar[j] + BN_EPS) + beta[j];
    out[g * FH + j] = fmaxf(z, 0.f);
}

extern "C" void kernel_launch(void* const* d_in, const int* in_sizes, int n_in,
                              void* d_out, int out_size, void* d_ws, size_t ws_size,
                              hipStream_t stream) {
    const float* feats = (const float*)d_in[0];
    const int*   edges = (const int*)d_in[1];
    const float* W0    = (const float*)d_in[2];
    const float* b0    = (const float*)d_in[3];
    const float* W1    = (const float*)d_in[4];
    const float* b1    = (const float*)d_in[5];
    const float* Wt    = (const float*)d_in[6];
    const float* bt    = (const float*)d_in[7];
    const float* gamma = (const float*)d_in[8];
    const float* beta  = (const float*)d_in[9];
    const float* rmean = (const float*)d_in[10];
    const float* rvar  = (const float*)d_in[11];
    float* out = (float*)d_out;

    // workspace layout
    char* w = (char*)d_ws;
    float* rs_out  = (float*)w;   w += sizeof(float) * NG * NN;
    float* rs_in   = (float*)w;   w += sizeof(float) * NG * NN;
    int*   row_ofs = (int*)w;     w += sizeof(int) * NG * 520;
    int*   csr_src = (int*)w;     w += sizeof(int) * ((size_t)NG * NE + 16);
    int*   csr_dst = (int*)w;     w += sizeof(int) * ((size_t)NG * NE + 16);
    unsigned short* WP = (unsigned short*)w;  w += sizeof(unsigned short) * 4 * 16384; // 128 KB
    unsigned short* Y1 = (unsigned short*)w;  w += sizeof(unsigned short) * (size_t)NG * NN * FH; // 16 MB
    unsigned short* Y2 = (unsigned short*)w;  w += sizeof(unsigned short) * (size_t)NG * NN * FH; // 16 MB
    float* partial = (float*)w;   w += sizeof(float) * NG * 8 * FH;

    unsigned short* WPh0 = WP;
    unsigned short* WPl0 = WP + 16384;
    unsigned short* WPh1 = WP + 32768;
    unsigned short* WPl1 = WP + 49152;

    // K1: build norms + CSR; 2 extra blocks pack W0/W1
    k_build<<<NG + 2, 1024, 0, stream>>>(edges, rs_out, rs_in, row_ofs, csr_src, csr_dst,
                                         W0, W1, WP);

    // K2: conv1 gemm (feats -> Y1, B-fragment packed), XCD = g%8
    k_gemm_f32<<<dim3(NG, 8), 256, 0, stream>>>(feats, WPh0, WPl0, rs_out, Y1);

    // K3: fused dense-A MFMA aggregation (LDS-staged B) + conv2 gemm (Y1 -> Y2, packed)
    k_fused<<<dim3(NG, 8), 512, 0, stream>>>(Y1, row_ofs, csr_src, csr_dst,
                                             rs_in, rs_out, b0, WPh1, WPl1, Y2);

    // K4: dense-A MFMA aggregation (LDS-staged B, conv2) + node-mean partials
    k_gather_mean<<<dim3(NG, 8), 512, 0, stream>>>(Y2, row_ofs, csr_src, csr_dst, rs_in, b1, partial);

    // K5: head
    k_head<<<NG, 128, 0, stream>>>(partial, Wt, bt, gamma, beta, rmean, rvar, out);

    (void)in_sizes; (void)n_in; (void)out_size; (void)ws_size;
}